// Round 11
// baseline (699.335 us; speedup 1.0000x reference)
//
#include <hip/hip_runtime.h>
#include <math.h>

#define B_  16
#define T_  16
#define N_  256
#define D_  384
#define Q_  384
#define K_  16
#define BT_ (B_ * T_)

// R11: ABLATION ROUND. Prefix variants P1..P4 (REPS-amplified, junk -> d_ws)
// decompose per-phase cost via rocprof per-dispatch durations. P5 = full
// kernel (identical math to R10), runs LAST and writes d_out.
// PHASES: 1=qproj, 2=+scores, 3=+topk, 4=+wsum, 5=+outproj(+store).
template<int PHASES, int REPS>
__global__ __launch_bounds__(1024, 4)
void fused_kernel(const float* __restrict__ queries,  // [BT_, Q_]
                  const float* __restrict__ patch,    // [BT_, N_, D_]
                  const float* __restrict__ W_in,     // [Q_, D_]
                  const float* __restrict__ b_in,     // [D_]
                  const float* __restrict__ W_out,    // [D_, Q_]
                  const float* __restrict__ b_out,    // [Q_]
                  float* __restrict__ junk,           // [BT_*1024] (d_ws)
                  float* __restrict__ out)            // [BT_, Q_]
{
    const int bt   = blockIdx.x;
    const int tid  = threadIdx.x;       // 0..1023
    const int lane = tid & 63;
    const int wave = tid >> 6;          // 0..15

    __shared__ __align__(16) float s_q[Q_];
    __shared__ __align__(16) float s_qp[D_];
    __shared__ __align__(16) float s_sc[N_];
    __shared__ __align__(16) int   s_cnt4[N_][4];
    __shared__ float s_red[4];
    __shared__ float s_red2[4][2];
    __shared__ float s_w[K_];
    __shared__ int   s_ix[K_];
    __shared__ __align__(16) float s_p8[8][D_];
    __shared__ __align__(16) float s_od[D_];

    const float* __restrict__ ptile = patch + (size_t)bt * N_ * D_;
    float* s_flat = &s_p8[0][0];

    if (tid < Q_) s_q[tid] = queries[(size_t)bt * Q_ + tid];
    __syncthreads();

    const int g16 = lane >> 4;
    const int sl  = lane & 15;
    const int n0  = wave * 4 + g16;

    float jk = 0.f;

    for (int r = 0; r < REPS; ++r) {

    float4 A[6], Bu[6];

#define LOADROW(dst, it) {                                                     \
        const float* pr = ptile + (size_t)(n0 + (it) * 64) * D_;               \
        _Pragma("unroll")                                                      \
        for (int c = 0; c < 6; ++c)                                            \
            dst[c] = *reinterpret_cast<const float4*>(pr + c * 64 + 4 * sl); }

#define DOTSTORE(src, it) {                                                    \
        float p = 0.f;                                                         \
        _Pragma("unroll")                                                      \
        for (int c = 0; c < 6; ++c)                                            \
            p += src[c].x * qv[c].x + src[c].y * qv[c].y                       \
               + src[c].z * qv[c].z + src[c].w * qv[c].w;                      \
        _Pragma("unroll")                                                      \
        for (int off = 8; off; off >>= 1) p += __shfl_xor(p, off, 16);         \
        if (sl == 0) s_sc[n0 + (it) * 64] = p; }

    if constexpr (PHASES >= 2) {
        LOADROW(A, 0)
        LOADROW(Bu, 1)
        __builtin_amdgcn_sched_barrier(0);
    }

    // ---- qproj: 768 thr, 8-way split-K, float4 W ----
    if (tid < 768) {
        const int s = tid / 96;
        const int g = tid % 96;
        float4 acc = {0.f, 0.f, 0.f, 0.f};
        const float* wp = W_in + (size_t)(s * 48) * D_ + 4 * g;
        #pragma unroll 4
        for (int qq = 0; qq < 48; ++qq) {
            const float4 w = *reinterpret_cast<const float4*>(wp + (size_t)qq * D_);
            const float qs = s_q[s * 48 + qq];
            acc.x += qs * w.x; acc.y += qs * w.y;
            acc.z += qs * w.z; acc.w += qs * w.w;
        }
        *reinterpret_cast<float4*>(&s_p8[s][4 * g]) = acc;
    }
    __syncthreads();
    if (tid < D_) {
        float v = b_in[tid];
        #pragma unroll
        for (int s = 0; s < 8; ++s) v += s_p8[s][tid];
        s_qp[tid] = v;
    }
    __syncthreads();
    jk += s_qp[(tid + r) % D_];

    if constexpr (PHASES >= 2) {
        // ---- scores ----
        {
            const float4* s_qp4 = reinterpret_cast<const float4*>(s_qp);
            float4 qv[6];
            #pragma unroll
            for (int c = 0; c < 6; ++c) qv[c] = s_qp4[c * 16 + sl];

            DOTSTORE(A, 0)
            LOADROW(A, 2)
            DOTSTORE(Bu, 1)
            LOADROW(Bu, 3)
            DOTSTORE(A, 2)
            DOTSTORE(Bu, 3)
        }
        __syncthreads();
        jk += s_sc[(tid + r) & (N_ - 1)];
    }
#undef LOADROW
#undef DOTSTORE

    float e = 0.f;
    int   cnt = N_;
    if constexpr (PHASES >= 3) {
        // ---- max + rank counts ----
        if (tid < N_) {
            float v = s_sc[tid];
            #pragma unroll
            for (int off = 32; off; off >>= 1) v = fmaxf(v, __shfl_xor(v, off));
            if (lane == 0) s_red[wave] = v;
        }
        {
            const int i   = tid >> 2;
            const int sub = tid & 3;
            const float si = s_sc[i];
            const float4* s_sc4 = reinterpret_cast<const float4*>(s_sc);
            int c = 0;
            #pragma unroll
            for (int jj = 0; jj < 16; ++jj) {
                const int jr = (jj + sub * 4) & 15;
                const float4 v = s_sc4[sub * 16 + jr];
                const int j0 = sub * 64 + jr * 4;
                c += (int)(v.x > si) | ((int)(v.x == si) & (int)((j0 + 0) < i));
                c += (int)(v.y > si) | ((int)(v.y == si) & (int)((j0 + 1) < i));
                c += (int)(v.z > si) | ((int)(v.z == si) & (int)((j0 + 2) < i));
                c += (int)(v.w > si) | ((int)(v.w == si) & (int)((j0 + 3) < i));
            }
            s_cnt4[i][sub] = c;
        }
        __syncthreads();

        if (tid < N_) {
            const float mx = fmaxf(fmaxf(s_red[0], s_red[1]), fmaxf(s_red[2], s_red[3]));
            const int4 c4 = reinterpret_cast<const int4*>(s_cnt4)[tid];
            cnt = c4.x + c4.y + c4.z + c4.w;
            e = __expf(s_sc[tid] - mx);

            float z  = e;
            float sk = (cnt < K_) ? e : 0.f;
            #pragma unroll
            for (int off = 32; off; off >>= 1) {
                z  += __shfl_xor(z, off);
                sk += __shfl_xor(sk, off);
            }
            if (lane == 0) { s_red2[wave][0] = z; s_red2[wave][1] = sk; }
        }
        __syncthreads();

        {
            const float Z  = s_red2[0][0] + s_red2[1][0] + s_red2[2][0] + s_red2[3][0];
            const float SK = s_red2[0][1] + s_red2[1][1] + s_red2[2][1] + s_red2[3][1];
            const float inv = 1.f / (SK + 1e-8f * Z);
            if (tid < N_ && cnt < K_) {
                s_ix[cnt] = tid;
                s_w[cnt]  = e * inv;
            }
        }
        __syncthreads();
        jk += s_w[(tid + r) & (K_ - 1)] + (float)s_ix[(tid + r) & (K_ - 1)];
    }

    if constexpr (PHASES >= 4) {
        // ---- weighted sum over K rows ----
        if (tid < 2 * D_) {
            const int half = tid >= D_;
            const int d    = tid - half * D_;
            const int j0   = half * (K_ / 2);
            float acc = 0.f;
            #pragma unroll
            for (int j = j0; j < j0 + K_ / 2; ++j)
                acc += s_w[j] * ptile[(size_t)s_ix[j] * D_ + d];
            s_flat[tid] = acc;
        }
        __syncthreads();
        if (tid < D_) s_od[tid] = s_flat[tid] + s_flat[tid + D_];
        __syncthreads();
        jk += s_od[(tid + r) % D_];
    }

    if constexpr (PHASES >= 5) {
        // ---- out-proj ----
        if (tid < 768) {
            const int s = tid / 96;
            const int g = tid % 96;
            float4 acc = {0.f, 0.f, 0.f, 0.f};
            const float* wp = W_out + (size_t)(s * 48) * Q_ + 4 * g;
            #pragma unroll 4
            for (int dd = 0; dd < 48; ++dd) {
                const float4 w = *reinterpret_cast<const float4*>(wp + (size_t)dd * Q_);
                const float ov = s_od[s * 48 + dd];
                acc.x += ov * w.x; acc.y += ov * w.y;
                acc.z += ov * w.z; acc.w += ov * w.w;
            }
            *reinterpret_cast<float4*>(&s_p8[s][4 * g]) = acc;
        }
        __syncthreads();
        if (tid < Q_) {
            float v = b_out[tid];
            #pragma unroll
            for (int s = 0; s < 8; ++s) v += s_p8[s][tid];
            out[(size_t)bt * Q_ + tid] = v;
        }
    }

    } // reps

    if constexpr (PHASES < 5)
        junk[(size_t)bt * 1024 + tid] = jk;
}

extern "C" void kernel_launch(void* const* d_in, const int* in_sizes, int n_in,
                              void* d_out, int out_size, void* d_ws, size_t ws_size,
                              hipStream_t stream) {
    const float* queries = (const float*)d_in[0];
    const float* patch   = (const float*)d_in[1];
    const float* W_in    = (const float*)d_in[2];
    const float* b_in    = (const float*)d_in[3];
    const float* W_out   = (const float*)d_in[4];
    const float* b_out   = (const float*)d_in[5];
    float* out  = (float*)d_out;
    float* junk = (float*)d_ws;

    // ablation variants (junk -> d_ws), REPS-amplified above the 58us fills
    fused_kernel<1, 16><<<dim3(BT_), dim3(1024), 0, stream>>>(
        queries, patch, W_in, b_in, W_out, b_out, junk, out);
    fused_kernel<2, 8><<<dim3(BT_), dim3(1024), 0, stream>>>(
        queries, patch, W_in, b_in, W_out, b_out, junk, out);
    fused_kernel<3, 8><<<dim3(BT_), dim3(1024), 0, stream>>>(
        queries, patch, W_in, b_in, W_out, b_out, junk, out);
    fused_kernel<4, 8><<<dim3(BT_), dim3(1024), 0, stream>>>(
        queries, patch, W_in, b_in, W_out, b_out, junk, out);
    // real kernel, runs last, writes d_out
    fused_kernel<5, 1><<<dim3(BT_), dim3(1024), 0, stream>>>(
        queries, patch, W_in, b_in, W_out, b_out, junk, out);
}

// Round 12
// 171.264 us; speedup vs baseline: 4.0834x; 4.0834x over previous
//
#include <hip/hip_runtime.h>
#include <math.h>

#define B_  16
#define T_  16
#define N_  256
#define D_  384
#define Q_  384
#define K_  16
#define BT_ (B_ * T_)
#define NT  512

// R12: split each bt across TWO 512-thread blocks (grid 512 = 2 blocks/CU).
// Block (bt,h): full qproj (redundant, L2-cheap) + scores for rows
// [h*128, h*128+128) -> ws. Deterministic atomic-join: per bt, the SECOND
// arriver (parity ticket on flags[bt], zeroed per call via hipMemsetAsync
// node) runs topk+wsum+outproj; the first exits. No global barrier, so
// different bts overlap phases on the same CU (R11: ~12us/rep of phase-
// boundary serialization at 1 block/CU was the biggest line item).
__global__ __launch_bounds__(NT, 4)
void fused_kernel(const float* __restrict__ queries,  // [BT_, Q_]
                  const float* __restrict__ patch,    // [BT_, N_, D_]
                  const float* __restrict__ W_in,     // [Q_, D_]
                  const float* __restrict__ b_in,     // [D_]
                  const float* __restrict__ W_out,    // [D_, Q_]
                  const float* __restrict__ b_out,    // [Q_]
                  float* __restrict__ scw,            // [BT_, N_] (d_ws)
                  unsigned int* __restrict__ flags,   // [BT_]     (d_ws)
                  float* __restrict__ out)            // [BT_, Q_]
{
    const int bx  = blockIdx.x;          // 0..511
    const int bt  = bx & (BT_ - 1);
    const int h   = bx >> 8;             // 0 or 1: score-row half
    const int tid = threadIdx.x;         // 0..511
    const int lane = tid & 63;
    const int wave = tid >> 6;           // 0..7

    __shared__ __align__(16) float s_q[Q_];
    __shared__ __align__(16) float s_qp[D_];
    __shared__ __align__(16) float s_p4[4][D_];
    __shared__ __align__(16) float s_sc[N_];
    __shared__ __align__(16) int   s_cnt2[N_][2];
    __shared__ float s_red[4];
    __shared__ float s_red2[4][2];
    __shared__ float s_w[K_];
    __shared__ int   s_ix[K_];
    __shared__ __align__(16) float s_od[D_];
    __shared__ unsigned int s_old;

    const float* __restrict__ ptile = patch + (size_t)bt * N_ * D_;

    if (tid < Q_) s_q[tid] = queries[(size_t)bt * Q_ + tid];
    __syncthreads();

    const int g  = tid >> 4;             // 0..31 (16-lane group)
    const int sl = tid & 15;

    float4 A[6], Bu[6];

#define LOADROW(dst, it) {                                                     \
        const float* pr = ptile + (size_t)(h * 128 + (it) * 32 + g) * D_;      \
        _Pragma("unroll")                                                      \
        for (int c = 0; c < 6; ++c)                                            \
            dst[c] = *reinterpret_cast<const float4*>(pr + c * 64 + 4 * sl); }

#define DOTSTORE(src, it) {                                                    \
        float p = 0.f;                                                         \
        _Pragma("unroll")                                                      \
        for (int c = 0; c < 6; ++c)                                            \
            p += src[c].x * qv[c].x + src[c].y * qv[c].y                       \
               + src[c].z * qv[c].z + src[c].w * qv[c].w;                      \
        _Pragma("unroll")                                                      \
        for (int off = 8; off; off >>= 1) p += __shfl_xor(p, off, 16);         \
        if (sl == 0) scw[(size_t)bt * N_ + h * 128 + (it) * 32 + g] = p; }

    // ---- prefetch first 2 score rows (independent of q_proj) ----
    LOADROW(A, 0)
    LOADROW(Bu, 1)
    __builtin_amdgcn_sched_barrier(0);

    // ---- qproj (full, redundant per half): 384 thr, 4-way split-K ----
    if (tid < 384) {
        const int s  = tid / 96;         // k-range [s*96, s*96+96)
        const int g2 = tid % 96;         // output cols 4g2..4g2+3
        float4 acc = {0.f, 0.f, 0.f, 0.f};
        const float* wp = W_in + (size_t)(s * 96) * D_ + 4 * g2;
        #pragma unroll 4
        for (int qq = 0; qq < 96; ++qq) {
            const float4 w = *reinterpret_cast<const float4*>(wp + (size_t)qq * D_);
            const float qs = s_q[s * 96 + qq];
            acc.x += qs * w.x; acc.y += qs * w.y;
            acc.z += qs * w.z; acc.w += qs * w.w;
        }
        *reinterpret_cast<float4*>(&s_p4[s][4 * g2]) = acc;
    }
    __syncthreads();
    if (tid < D_)
        s_qp[tid] = b_in[tid] + s_p4[0][tid] + s_p4[1][tid]
                              + s_p4[2][tid] + s_p4[3][tid];
    __syncthreads();

    // ---- scores for this half: 32 groups x 4 rows, 2-deep pipeline ----
    {
        const float4* s_qp4 = reinterpret_cast<const float4*>(s_qp);
        float4 qv[6];
        #pragma unroll
        for (int c = 0; c < 6; ++c) qv[c] = s_qp4[c * 16 + sl];

        DOTSTORE(A, 0)
        LOADROW(A, 2)
        DOTSTORE(Bu, 1)
        LOADROW(Bu, 3)
        DOTSTORE(A, 2)
        DOTSTORE(Bu, 3)
    }
#undef LOADROW
#undef DOTSTORE

    // ---- join: release own stores, take ticket; second arriver continues ----
    __threadfence();
    __syncthreads();
    if (tid == 0) s_old = atomicAdd(&flags[bt], 1u);
    __syncthreads();
    if ((s_old & 1u) == 0u) return;      // first arriver exits
    __threadfence();                     // acquire other half's stores

    if (tid < N_) s_sc[tid] = scw[(size_t)bt * N_ + tid];
    __syncthreads();

    // ---- block max (waves 0-3) + rank counts (512 thr, 2-way sub-split) ----
    if (tid < N_) {
        float v = s_sc[tid];
        #pragma unroll
        for (int off = 32; off; off >>= 1) v = fmaxf(v, __shfl_xor(v, off));
        if (lane == 0) s_red[wave] = v;
    }
    {
        const int i   = tid >> 1;        // 0..255
        const int sub = tid & 1;         // chunk [sub*128, sub*128+128)
        const float si = s_sc[i];
        const float4* s_sc4 = reinterpret_cast<const float4*>(s_sc);
        int c = 0;
        #pragma unroll
        for (int jj = 0; jj < 32; ++jj) {
            const float4 v = s_sc4[sub * 32 + jj];   // broadcast per sub
            const int j0 = sub * 128 + jj * 4;
            c += (int)(v.x > si) | ((int)(v.x == si) & (int)((j0 + 0) < i));
            c += (int)(v.y > si) | ((int)(v.y == si) & (int)((j0 + 1) < i));
            c += (int)(v.z > si) | ((int)(v.z == si) & (int)((j0 + 2) < i));
            c += (int)(v.w > si) | ((int)(v.w == si) & (int)((j0 + 3) < i));
        }
        s_cnt2[i][sub] = c;
    }
    __syncthreads();

    // ---- e, Z, SK (threads < 256) ----
    float e = 0.f;
    int   cnt = N_;
    if (tid < N_) {
        const float mx = fmaxf(fmaxf(s_red[0], s_red[1]), fmaxf(s_red[2], s_red[3]));
        const int2 c2 = reinterpret_cast<const int2*>(s_cnt2)[tid];
        cnt = c2.x + c2.y;
        e = __expf(s_sc[tid] - mx);

        float z  = e;
        float sk = (cnt < K_) ? e : 0.f;
        #pragma unroll
        for (int off = 32; off; off >>= 1) {
            z  += __shfl_xor(z, off);
            sk += __shfl_xor(sk, off);
        }
        if (lane == 0) { s_red2[wave][0] = z; s_red2[wave][1] = sk; }
    }
    __syncthreads();

    // weight_i = softmax_i / (sum_topk + EPS) = e_i / (SK + EPS*Z)
    {
        const float Z  = s_red2[0][0] + s_red2[1][0] + s_red2[2][0] + s_red2[3][0];
        const float SK = s_red2[0][1] + s_red2[1][1] + s_red2[2][1] + s_red2[3][1];
        const float inv = 1.f / (SK + 1e-8f * Z);
        if (tid < N_ && cnt < K_) {
            s_ix[cnt] = tid;
            s_w[cnt]  = e * inv;
        }
    }
    __syncthreads();

    // ---- weighted sum over K rows: 384 thr, serial 16 (rows are L2/L3-hot) --
    if (tid < D_) {
        float acc = 0.f;
        #pragma unroll
        for (int j = 0; j < K_; ++j)
            acc += s_w[j] * ptile[(size_t)s_ix[j] * D_ + tid];
        s_od[tid] = acc;
    }
    __syncthreads();

    // ---- out-proj: 384 thr, 4-way split-K, float4 W loads ----
    if (tid < 384) {
        const int s  = tid / 96;
        const int g2 = tid % 96;
        float4 acc = {0.f, 0.f, 0.f, 0.f};
        const float* wp = W_out + (size_t)(s * 96) * Q_ + 4 * g2;
        #pragma unroll 4
        for (int dd = 0; dd < 96; ++dd) {
            const float4 w = *reinterpret_cast<const float4*>(wp + (size_t)dd * Q_);
            const float ov = s_od[s * 96 + dd];
            acc.x += ov * w.x; acc.y += ov * w.y;
            acc.z += ov * w.z; acc.w += ov * w.w;
        }
        *reinterpret_cast<float4*>(&s_p4[s][4 * g2]) = acc;
    }
    __syncthreads();
    if (tid < Q_)
        out[(size_t)bt * Q_ + tid] = b_out[tid] + s_p4[0][tid] + s_p4[1][tid]
                                               + s_p4[2][tid] + s_p4[3][tid];
}

extern "C" void kernel_launch(void* const* d_in, const int* in_sizes, int n_in,
                              void* d_out, int out_size, void* d_ws, size_t ws_size,
                              hipStream_t stream) {
    const float* queries = (const float*)d_in[0];
    const float* patch   = (const float*)d_in[1];
    const float* W_in    = (const float*)d_in[2];
    const float* b_in    = (const float*)d_in[3];
    const float* W_out   = (const float*)d_in[4];
    const float* b_out   = (const float*)d_in[5];
    float* out = (float*)d_out;

    float* scw = (float*)d_ws;                              // [BT_, N_]
    unsigned int* flags = (unsigned int*)(scw + BT_ * N_);  // [BT_]

    hipMemsetAsync(flags, 0, BT_ * sizeof(unsigned int), stream);
    fused_kernel<<<dim3(2 * BT_), dim3(NT), 0, stream>>>(
        queries, patch, W_in, b_in, W_out, b_out, scw, flags, out);
}

// Round 13
// 34.460 us; speedup vs baseline: 20.2941x; 4.9699x over previous
//
#include <hip/hip_runtime.h>
#include <math.h>

#define B_  16
#define T_  16
#define N_  256
#define D_  384
#define Q_  384
#define K_  16
#define BT_ (B_ * T_)

// R13 = R10 (best, 35.67us) + 3-row patch prefetch before qproj.
// R9/R10 counters showed VGPR=48-52 with 12 float4 prefetch live across the
// qproj GEMV -> compiler parks prefetch in AGPRs (gfx950 unified file), so a
// 3-deep prefetch fits the 128-reg/16-wave budget. qproj (~4.3us L2 GEMV)
// now overlaps 75% of the block's 393KB patch stream.
// R12 lesson: NO cross-block joins — __threadfence = L2 writeback on CDNA4.
__global__ __launch_bounds__(1024, 4)
void fused_kernel(const float* __restrict__ queries,  // [BT_, Q_]
                  const float* __restrict__ patch,    // [BT_, N_, D_]
                  const float* __restrict__ W_in,     // [Q_, D_]
                  const float* __restrict__ b_in,     // [D_]
                  const float* __restrict__ W_out,    // [D_, Q_]
                  const float* __restrict__ b_out,    // [Q_]
                  float* __restrict__ out)            // [BT_, Q_]
{
    const int bt   = blockIdx.x;
    const int tid  = threadIdx.x;       // 0..1023
    const int lane = tid & 63;
    const int wave = tid >> 6;          // 0..15

    __shared__ __align__(16) float s_q[Q_];
    __shared__ __align__(16) float s_qp[D_];
    __shared__ __align__(16) float s_sc[N_];
    __shared__ __align__(16) int   s_cnt4[N_][4];
    __shared__ float s_red[4];
    __shared__ float s_red2[4][2];
    __shared__ float s_w[K_];
    __shared__ int   s_ix[K_];
    __shared__ __align__(16) float s_p8[8][D_];   // split-K partials (reused)
    __shared__ __align__(16) float s_od[D_];

    const float* __restrict__ ptile = patch + (size_t)bt * N_ * D_;
    float* s_flat = &s_p8[0][0];

    // ---- stage query row ----
    if (tid < Q_) s_q[tid] = queries[(size_t)bt * Q_ + tid];
    __syncthreads();

    const int g16 = lane >> 4;          // 0..3
    const int sl  = lane & 15;
    const int n0  = wave * 4 + g16;     // rows n0 + {0,64,128,192}

    float4 A[6], Bu[6], C[6];

#define LOADROW(dst, it) {                                                     \
        const float* pr = ptile + (size_t)(n0 + (it) * 64) * D_;               \
        _Pragma("unroll")                                                      \
        for (int c = 0; c < 6; ++c)                                            \
            dst[c] = *reinterpret_cast<const float4*>(pr + c * 64 + 4 * sl); }

#define DOTSTORE(src, it) {                                                    \
        float p = 0.f;                                                         \
        _Pragma("unroll")                                                      \
        for (int c = 0; c < 6; ++c)                                            \
            p += src[c].x * qv[c].x + src[c].y * qv[c].y                       \
               + src[c].z * qv[c].z + src[c].w * qv[c].w;                      \
        _Pragma("unroll")                                                      \
        for (int off = 8; off; off >>= 1) p += __shfl_xor(p, off, 16);         \
        if (sl == 0) s_sc[n0 + (it) * 64] = p; }

    // ---- issue patch prefetch rows 0,1,2 (independent of q_proj) ----
    LOADROW(A, 0)
    LOADROW(Bu, 1)
    LOADROW(C, 2)
    __builtin_amdgcn_sched_barrier(0);  // pin prefetch issue before qproj

    // ---- q_proj while prefetch streams: 768 thr, 8-way split-K, float4 W ----
    if (tid < 768) {
        const int s = tid / 96;         // k-split 0..7 -> q in [s*48, s*48+48)
        const int g = tid % 96;         // output cols 4g..4g+3
        float4 acc = {0.f, 0.f, 0.f, 0.f};
        const float* wp = W_in + (size_t)(s * 48) * D_ + 4 * g;
        #pragma unroll 4
        for (int qq = 0; qq < 48; ++qq) {
            const float4 w = *reinterpret_cast<const float4*>(wp + (size_t)qq * D_);
            const float qs = s_q[s * 48 + qq];
            acc.x += qs * w.x; acc.y += qs * w.y;
            acc.z += qs * w.z; acc.w += qs * w.w;
        }
        *reinterpret_cast<float4*>(&s_p8[s][4 * g]) = acc;
    }
    __syncthreads();
    if (tid < D_) {
        float v = b_in[tid];
        #pragma unroll
        for (int s = 0; s < 8; ++s) v += s_p8[s][tid];
        s_qp[tid] = v;
    }
    __syncthreads();   // prefetch has arrived under qproj

    // ---- scores: rows 0,1,2 from prefetch; row 3 pipelined ----
    {
        const float4* s_qp4 = reinterpret_cast<const float4*>(s_qp);
        float4 qv[6];
        #pragma unroll
        for (int c = 0; c < 6; ++c) qv[c] = s_qp4[c * 16 + sl];

        DOTSTORE(A, 0)
        LOADROW(A, 3)
        DOTSTORE(Bu, 1)
        DOTSTORE(C, 2)
        DOTSTORE(A, 3)
    }
#undef LOADROW
#undef DOTSTORE
    __syncthreads();

    // ---- block max (waves 0-3) + rank counts (rotated float4, conflict-free) 
    if (tid < N_) {
        float v = s_sc[tid];
        #pragma unroll
        for (int off = 32; off; off >>= 1) v = fmaxf(v, __shfl_xor(v, off));
        if (lane == 0) s_red[wave] = v;
    }
    {
        const int i   = tid >> 2;       // 0..255
        const int sub = tid & 3;        // chunk [sub*64, sub*64+64)
        const float si = s_sc[i];
        const float4* s_sc4 = reinterpret_cast<const float4*>(s_sc);
        int c = 0;
        #pragma unroll
        for (int jj = 0; jj < 16; ++jj) {
            const int jr = (jj + sub * 4) & 15;          // rotate start
            const float4 v = s_sc4[sub * 16 + jr];
            const int j0 = sub * 64 + jr * 4;
            c += (int)(v.x > si) | ((int)(v.x == si) & (int)((j0 + 0) < i));
            c += (int)(v.y > si) | ((int)(v.y == si) & (int)((j0 + 1) < i));
            c += (int)(v.z > si) | ((int)(v.z == si) & (int)((j0 + 2) < i));
            c += (int)(v.w > si) | ((int)(v.w == si) & (int)((j0 + 3) < i));
        }
        s_cnt4[i][sub] = c;
    }
    __syncthreads();

    // ---- e, Z, SK (threads < 256) ----
    float e = 0.f;
    int   cnt = N_;
    if (tid < N_) {
        const float mx = fmaxf(fmaxf(s_red[0], s_red[1]), fmaxf(s_red[2], s_red[3]));
        const int4 c4 = reinterpret_cast<const int4*>(s_cnt4)[tid];
        cnt = c4.x + c4.y + c4.z + c4.w;
        e = __expf(s_sc[tid] - mx);

        float z  = e;
        float sk = (cnt < K_) ? e : 0.f;
        #pragma unroll
        for (int off = 32; off; off >>= 1) {
            z  += __shfl_xor(z, off);
            sk += __shfl_xor(sk, off);
        }
        if (lane == 0) { s_red2[wave][0] = z; s_red2[wave][1] = sk; }
    }
    __syncthreads();

    // weight_i = softmax_i / (sum_topk + EPS) = e_i / (SK + EPS*Z)
    {
        const float Z  = s_red2[0][0] + s_red2[1][0] + s_red2[2][0] + s_red2[3][0];
        const float SK = s_red2[0][1] + s_red2[1][1] + s_red2[2][1] + s_red2[3][1];
        const float inv = 1.f / (SK + 1e-8f * Z);
        if (tid < N_ && cnt < K_) {
            s_ix[cnt] = tid;
            s_w[cnt]  = e * inv;
        }
    }
    __syncthreads();

    // ---- weighted sum over K rows: 768 thr, 2-way split over j ----
    if (tid < 2 * D_) {
        const int half = tid >= D_;
        const int d    = tid - half * D_;
        const int j0   = half * (K_ / 2);
        float acc = 0.f;
        #pragma unroll
        for (int j = j0; j < j0 + K_ / 2; ++j)
            acc += s_w[j] * ptile[(size_t)s_ix[j] * D_ + d];
        s_flat[tid] = acc;
    }
    __syncthreads();
    if (tid < D_) s_od[tid] = s_flat[tid] + s_flat[tid + D_];
    __syncthreads();

    // ---- out-proj: 768 thr, 8-way split-K, float4 W loads ----
    if (tid < 768) {
        const int s = tid / 96;         // k-split: d in [s*48, s*48+48)
        const int g = tid % 96;         // output cols 4g..4g+3
        float4 acc = {0.f, 0.f, 0.f, 0.f};
        const float* wp = W_out + (size_t)(s * 48) * Q_ + 4 * g;
        #pragma unroll 4
        for (int dd = 0; dd < 48; ++dd) {
            const float4 w = *reinterpret_cast<const float4*>(wp + (size_t)dd * Q_);
            const float ov = s_od[s * 48 + dd];
            acc.x += ov * w.x; acc.y += ov * w.y;
            acc.z += ov * w.z; acc.w += ov * w.w;
        }
        *reinterpret_cast<float4*>(&s_p8[s][4 * g]) = acc;
    }
    __syncthreads();
    if (tid < Q_) {
        float v = b_out[tid];
        #pragma unroll
        for (int s = 0; s < 8; ++s) v += s_p8[s][tid];
        out[(size_t)bt * Q_ + tid] = v;
    }
}

extern "C" void kernel_launch(void* const* d_in, const int* in_sizes, int n_in,
                              void* d_out, int out_size, void* d_ws, size_t ws_size,
                              hipStream_t stream) {
    const float* queries = (const float*)d_in[0];
    const float* patch   = (const float*)d_in[1];
    const float* W_in    = (const float*)d_in[2];
    const float* b_in    = (const float*)d_in[3];
    const float* W_out   = (const float*)d_in[4];
    const float* b_out   = (const float*)d_in[5];
    float* out = (float*)d_out;

    fused_kernel<<<dim3(BT_), dim3(1024), 0, stream>>>(
        queries, patch, W_in, b_in, W_out, b_out, out);
}

// Round 14
// 32.670 us; speedup vs baseline: 21.4060x; 1.0548x over previous
//
#include <hip/hip_runtime.h>
#include <math.h>

#define B_  16
#define T_  16
#define N_  256
#define D_  384
#define Q_  384
#define K_  16
#define BT_ (B_ * T_)

// R14 = R13 + tail-cheapening:
//  1. top-K rank count via u32 keys (ord(score)&~255 | (255-idx)): 2 VALU/elem
//     instead of ~6; keys injective -> permutation ranks, deterministic.
//  2. wsum merged to one pass (384 thr, 4 chains), one barrier fewer.
//  3. outproj W_out prefetch (8 float4/thr) issued before wsum.
__global__ __launch_bounds__(1024, 4)
void fused_kernel(const float* __restrict__ queries,  // [BT_, Q_]
                  const float* __restrict__ patch,    // [BT_, N_, D_]
                  const float* __restrict__ W_in,     // [Q_, D_]
                  const float* __restrict__ b_in,     // [D_]
                  const float* __restrict__ W_out,    // [D_, Q_]
                  const float* __restrict__ b_out,    // [Q_]
                  float* __restrict__ out)            // [BT_, Q_]
{
    const int bt   = blockIdx.x;
    const int tid  = threadIdx.x;       // 0..1023
    const int lane = tid & 63;
    const int wave = tid >> 6;          // 0..15

    __shared__ __align__(16) float s_q[Q_];
    __shared__ __align__(16) float s_qp[D_];
    __shared__ __align__(16) float s_sc[N_];
    __shared__ __align__(16) unsigned s_ku[N_];   // rank keys
    __shared__ __align__(16) int   s_cnt4[N_][4];
    __shared__ float s_red[4];
    __shared__ float s_red2[4][2];
    __shared__ float s_w[K_];
    __shared__ int   s_ix[K_];
    __shared__ __align__(16) float s_p8[8][D_];   // split-K partials (reused)
    __shared__ __align__(16) float s_od[D_];

    const float* __restrict__ ptile = patch + (size_t)bt * N_ * D_;

    // ---- stage query row ----
    if (tid < Q_) s_q[tid] = queries[(size_t)bt * Q_ + tid];
    __syncthreads();

    const int g16 = lane >> 4;          // 0..3
    const int sl  = lane & 15;
    const int n0  = wave * 4 + g16;     // rows n0 + {0,64,128,192}

    float4 A[6], Bu[6], C[6];

#define LOADROW(dst, it) {                                                     \
        const float* pr = ptile + (size_t)(n0 + (it) * 64) * D_;               \
        _Pragma("unroll")                                                      \
        for (int c = 0; c < 6; ++c)                                            \
            dst[c] = *reinterpret_cast<const float4*>(pr + c * 64 + 4 * sl); }

#define DOTSTORE(src, it) {                                                    \
        float p = 0.f;                                                         \
        _Pragma("unroll")                                                      \
        for (int c = 0; c < 6; ++c)                                            \
            p += src[c].x * qv[c].x + src[c].y * qv[c].y                       \
               + src[c].z * qv[c].z + src[c].w * qv[c].w;                      \
        _Pragma("unroll")                                                      \
        for (int off = 8; off; off >>= 1) p += __shfl_xor(p, off, 16);         \
        if (sl == 0) {                                                         \
            const int nn = n0 + (it) * 64;                                     \
            s_sc[nn] = p;                                                      \
            const unsigned u = __float_as_uint(p);                             \
            const unsigned ord = u ^ ((unsigned)((int)u >> 31) | 0x80000000u); \
            s_ku[nn] = (ord & 0xFFFFFF00u) | (255u - (unsigned)nn);            \
        } }

    // ---- issue patch prefetch rows 0,1,2 (independent of q_proj) ----
    LOADROW(A, 0)
    LOADROW(Bu, 1)
    LOADROW(C, 2)
    __builtin_amdgcn_sched_barrier(0);  // pin prefetch issue before qproj

    // ---- q_proj while prefetch streams: 768 thr, 8-way split-K, float4 W ----
    if (tid < 768) {
        const int s = tid / 96;         // k-split 0..7 -> q in [s*48, s*48+48)
        const int g = tid % 96;         // output cols 4g..4g+3
        float4 acc = {0.f, 0.f, 0.f, 0.f};
        const float* wp = W_in + (size_t)(s * 48) * D_ + 4 * g;
        #pragma unroll 4
        for (int qq = 0; qq < 48; ++qq) {
            const float4 w = *reinterpret_cast<const float4*>(wp + (size_t)qq * D_);
            const float qs = s_q[s * 48 + qq];
            acc.x += qs * w.x; acc.y += qs * w.y;
            acc.z += qs * w.z; acc.w += qs * w.w;
        }
        *reinterpret_cast<float4*>(&s_p8[s][4 * g]) = acc;
    }
    __syncthreads();
    if (tid < D_) {
        float v = b_in[tid];
        #pragma unroll
        for (int s = 0; s < 8; ++s) v += s_p8[s][tid];
        s_qp[tid] = v;
    }
    __syncthreads();   // prefetch has arrived under qproj

    // ---- scores: rows 0,1,2 from prefetch; row 3 pipelined ----
    {
        const float4* s_qp4 = reinterpret_cast<const float4*>(s_qp);
        float4 qv[6];
        #pragma unroll
        for (int c = 0; c < 6; ++c) qv[c] = s_qp4[c * 16 + sl];

        DOTSTORE(A, 0)
        LOADROW(A, 3)
        DOTSTORE(Bu, 1)
        DOTSTORE(C, 2)
        DOTSTORE(A, 3)
    }
#undef LOADROW
#undef DOTSTORE
    __syncthreads();

    // ---- block max (waves 0-3) + key rank counts (all 1024 thr, rotated) ----
    if (tid < N_) {
        float v = s_sc[tid];
        #pragma unroll
        for (int off = 32; off; off >>= 1) v = fmaxf(v, __shfl_xor(v, off));
        if (lane == 0) s_red[wave] = v;
    }
    {
        const int i   = tid >> 2;       // 0..255
        const int sub = tid & 3;        // chunk [sub*64, sub*64+64)
        const unsigned ki = s_ku[i];
        const uint4* k4 = reinterpret_cast<const uint4*>(s_ku);
        int c = 0;
        #pragma unroll
        for (int jj = 0; jj < 16; ++jj) {
            const int jr = (jj + sub * 4) & 15;          // rotate start
            const uint4 v = k4[sub * 16 + jr];
            c += (int)(v.x > ki) + (int)(v.y > ki)
               + (int)(v.z > ki) + (int)(v.w > ki);
        }
        s_cnt4[i][sub] = c;
    }
    __syncthreads();

    // ---- e, Z, SK (threads < 256) ----
    float e = 0.f;
    int   cnt = N_;
    if (tid < N_) {
        const float mx = fmaxf(fmaxf(s_red[0], s_red[1]), fmaxf(s_red[2], s_red[3]));
        const int4 c4 = reinterpret_cast<const int4*>(s_cnt4)[tid];
        cnt = c4.x + c4.y + c4.z + c4.w;
        e = __expf(s_sc[tid] - mx);

        float z  = e;
        float sk = (cnt < K_) ? e : 0.f;
        #pragma unroll
        for (int off = 32; off; off >>= 1) {
            z  += __shfl_xor(z, off);
            sk += __shfl_xor(sk, off);
        }
        if (lane == 0) { s_red2[wave][0] = z; s_red2[wave][1] = sk; }
    }
    __syncthreads();

    // weight_i = softmax_i / (sum_topk + EPS) = e_i / (SK + EPS*Z)
    {
        const float Z  = s_red2[0][0] + s_red2[1][0] + s_red2[2][0] + s_red2[3][0];
        const float SK = s_red2[0][1] + s_red2[1][1] + s_red2[2][1] + s_red2[3][1];
        const float inv = 1.f / (SK + 1e-8f * Z);
        if (tid < N_ && cnt < K_) {
            s_ix[cnt] = tid;
            s_w[cnt]  = e * inv;
        }
    }
    __syncthreads();

    // ---- W_out prefetch (independent of s_od) + weighted sum over K rows ----
    float4 wpre[8];
    const float* wp = W_out;
    if (tid < 768) {
        const int s = tid / 96;
        const int g = tid % 96;
        wp = W_out + (size_t)(s * 48) * Q_ + 4 * g;
        #pragma unroll
        for (int p = 0; p < 8; ++p)
            wpre[p] = *reinterpret_cast<const float4*>(wp + (size_t)p * Q_);
    }
    __builtin_amdgcn_sched_barrier(0);  // issue W_out loads before wsum

    if (tid < D_) {
        float a0 = 0.f, a1 = 0.f, a2 = 0.f, a3 = 0.f;
        #pragma unroll
        for (int j = 0; j < K_; j += 4) {
            a0 += s_w[j + 0] * ptile[(size_t)s_ix[j + 0] * D_ + tid];
            a1 += s_w[j + 1] * ptile[(size_t)s_ix[j + 1] * D_ + tid];
            a2 += s_w[j + 2] * ptile[(size_t)s_ix[j + 2] * D_ + tid];
            a3 += s_w[j + 3] * ptile[(size_t)s_ix[j + 3] * D_ + tid];
        }
        s_od[tid] = (a0 + a1) + (a2 + a3);
    }
    __syncthreads();

    // ---- out-proj: 768 thr, 8-way split-K; 8 prefetched + 40 streamed ----
    if (tid < 768) {
        const int s = tid / 96;
        const int g = tid % 96;
        const int base = s * 48;
        float4 acc = {0.f, 0.f, 0.f, 0.f};
        #pragma unroll
        for (int p = 0; p < 8; ++p) {
            const float ov = s_od[base + p];
            acc.x += ov * wpre[p].x; acc.y += ov * wpre[p].y;
            acc.z += ov * wpre[p].z; acc.w += ov * wpre[p].w;
        }
        #pragma unroll 4
        for (int dd = 8; dd < 48; ++dd) {
            const float4 w = *reinterpret_cast<const float4*>(wp + (size_t)dd * Q_);
            const float ov = s_od[base + dd];
            acc.x += ov * w.x; acc.y += ov * w.y;
            acc.z += ov * w.z; acc.w += ov * w.w;
        }
        *reinterpret_cast<float4*>(&s_p8[s][4 * g]) = acc;
    }
    __syncthreads();
    if (tid < Q_) {
        float v = b_out[tid];
        #pragma unroll
        for (int s = 0; s < 8; ++s) v += s_p8[s][tid];
        out[(size_t)bt * Q_ + tid] = v;
    }
}

extern "C" void kernel_launch(void* const* d_in, const int* in_sizes, int n_in,
                              void* d_out, int out_size, void* d_ws, size_t ws_size,
                              hipStream_t stream) {
    const float* queries = (const float*)d_in[0];
    const float* patch   = (const float*)d_in[1];
    const float* W_in    = (const float*)d_in[2];
    const float* b_in    = (const float*)d_in[3];
    const float* W_out   = (const float*)d_in[4];
    const float* b_out   = (const float*)d_in[5];
    float* out = (float*)d_out;

    fused_kernel<<<dim3(BT_), dim3(1024), 0, stream>>>(
        queries, patch, W_in, b_in, W_out, b_out, out);
}